// Round 5
// baseline (366.562 us; speedup 1.0000x reference)
//
#include <hip/hip_runtime.h>
#include <stdint.h>

#define TPB   256
#define D_DIM 4096
#define EPW   16      // elements per thread = D/TPB
#define NBIN  1024
#define CAP   256     // boundary-bin candidate capacity
#define NQ    (CAP/64)
#define KSEL  16
#define HI_T  512u    // bin >= HI_T  <=> |z| >= 2.0
#define LO_T  496u    // bin <  LO_T  <=> |z| <  0.125

// ws layout (floats)
#define WS_STDP 0
#define WS_INV  D_DIM
#define WS_SCAL (2*D_DIM)   // [0]=tau [1]=beta_up [2]=gamma [3]=beta_fam [4]=inv_e_norm

struct SMem {
    unsigned int hist[NBIN];              // 4 KB
    unsigned long long lists[2 * CAP];    // 4 KB
    unsigned char mark[D_DIM];            // 4 KB: 0=none 1=top-winner 2=bot-winner
    float red[4][2];
    unsigned int cnt[4];                  // 0=top list, 1=bot list, 2=tailTop, 3=tailBot
};

__device__ __forceinline__ float fast_rcp(float v)  { return __builtin_amdgcn_rcpf(v); }
__device__ __forceinline__ float fast_exp2(float v) { return __builtin_amdgcn_exp2f(v); }

// gelu(x) = 0.5x(1+tanh(u)) = x * sigmoid(2u), u = c*(x + 0.044715 x^3)
#define GELU_AN (-2.30220819f)   // -2c*log2e
#define GELU_BN (-0.10294331f)   // -2c*0.044715*log2e
#define TWO_LOG2E (2.8853900817779268f)

__device__ __forceinline__ float gelu_fast(float x) {
    float x2 = x * x;
    float s  = fmaf(x2, GELU_BN, GELU_AN);
    float nq = x * s;
    float ex = fast_exp2(nq);
    return x * fast_rcp(1.0f + ex);
}

__device__ __forceinline__ float tanh_fast_pm(float y2l) {
    float ex = fast_exp2(y2l);
    float r  = fast_rcp(1.0f + ex);
    return fmaf(-2.0f, r, 1.0f);
}

__device__ __forceinline__ float top_gate(float zz, float beta_up, float kg) {
    float g = fmaf(beta_up, tanh_fast_pm(zz * kg), 1.0f);
    return fminf(fmaxf(g, 0.1f), 8.0f);
}

// ---- precompute: per-column stdp/inv + scalars (1 block) ----
__global__ __launch_bounds__(TPB) void precomp(
    const float* __restrict__ em, const float* __restrict__ eq,
    const float* __restrict__ eo,
    const float* __restrict__ lt, const float* __restrict__ lb,
    const float* __restrict__ lg, const float* __restrict__ lf,
    float* __restrict__ ws)
{
    __shared__ float red[4];
    const int tid = threadIdx.x;
    float e2 = 0.0f;
    for (int i = 0; i < D_DIM / TPB; ++i) {
        const int d = i * TPB + tid;
        const float mu  = em[d];
        const float mu2 = __fmul_rn(mu, mu);
        float var = __fsub_rn(eq[d], mu2);
        var = fmaxf(var, 1e-4f);
        const float stdp = __fadd_rn(sqrtf(var), 1e-5f);  // bit-identical to numpy std+EPS
        ws[WS_STDP + d] = stdp;
        ws[WS_INV + d]  = 1.0f / stdp;
        const float e = eo[d];
        e2 = fmaf(e, e, e2);
    }
    #pragma unroll
    for (int off = 32; off; off >>= 1) e2 += __shfl_xor(e2, off);
    if ((tid & 63) == 0) red[tid >> 6] = e2;
    __syncthreads();
    if (tid == 0) {
        const float t  = red[0] + red[1] + red[2] + red[3];
        const float en = sqrtf(t);
        ws[WS_SCAL + 0] = expf(lt[0]);
        ws[WS_SCAL + 1] = log1pf(expf(lb[0]));
        ws[WS_SCAL + 2] = log1pf(expf(lg[0]));
        ws[WS_SCAL + 3] = 1.0f / (1.0f + expf(-lf[0]));
        ws[WS_SCAL + 4] = 1.0f / fmaxf(en, 1e-12f);
    }
}

__global__ __launch_bounds__(TPB, 6) void fused_gelu_gate(
    const float* __restrict__ x,
    const float* __restrict__ ema_mean,
    const float* __restrict__ ema_out,
    const float* __restrict__ ws,
    float* __restrict__ out)
{
    __shared__ SMem sh;
    const int tid = threadIdx.x;
    const int ln  = tid & 63;
    const int wv  = tid >> 6;
    const long long base = (long long)blockIdx.x * D_DIM;

    // ---- init hist + mark + counters ----
    #pragma unroll
    for (int i = 0; i < NBIN / TPB; ++i) sh.hist[tid + i * TPB] = 0u;
    unsigned int* mrk32 = (unsigned int*)sh.mark;
    #pragma unroll
    for (int i = 0; i < (D_DIM / 4) / TPB; ++i) mrk32[tid + i * TPB] = 0u;
    if (tid < 4) sh.cnt[tid] = 0u;
    __syncthreads();                                   // B1

    const float tau      = ws[WS_SCAL + 0];
    const float beta_up  = ws[WS_SCAL + 1];
    const float kg       = ws[WS_SCAL + 2] * TWO_LOG2E;  // gamma * 2log2e
    const float beta_fam = ws[WS_SCAL + 3];
    const float inv_en   = ws[WS_SCAL + 4];

    float z_r[EPW];
    float s_o2 = 0.0f, s_dot = 0.0f;
    unsigned int lt_c = 0u, lb_c = 0u;

    // ---- pass 1: load, fast gelu (for sums only), fast z (kept), tail histogram ----
    #pragma unroll
    for (int i = 0; i < EPW / 4; ++i) {
        const int off = (i * TPB + tid) * 4;
        const float4 xv = *(const float4*)(x + base + off);
        const float4 mv = *(const float4*)(ema_mean + off);
        const float4 iv = *(const float4*)(ws + WS_INV + off);
        const float4 ev = *(const float4*)(ema_out + off);
        const float xs[4] = {xv.x, xv.y, xv.z, xv.w};
        const float ms[4] = {mv.x, mv.y, mv.z, mv.w};
        const float is[4] = {iv.x, iv.y, iv.z, iv.w};
        const float es[4] = {ev.x, ev.y, ev.z, ev.w};
        #pragma unroll
        for (int j = 0; j < 4; ++j) {
            const int e = i * 4 + j;
            const float xx = xs[j];
            const float zz = (xx - ms[j]) * is[j];
            const float og = gelu_fast(xx);
            z_r[e] = zz;
            s_o2  = fmaf(og, og, s_o2);
            s_dot = fmaf(og, es[j], s_dot);
            const unsigned int bits = __float_as_uint(zz) & 0x7fffffffu;
            const unsigned int b = bits >> 21;
            if (b >= HI_T)     { ++lt_c; atomicAdd(&sh.hist[b], 1u); }
            else if (b < LO_T) { ++lb_c; atomicAdd(&sh.hist[b], 1u); }
        }
    }

    // ---- block-reduce sums + tail counts ----
    #pragma unroll
    for (int off = 32; off; off >>= 1) {
        s_o2  += __shfl_xor(s_o2, off);
        s_dot += __shfl_xor(s_dot, off);
        lt_c  += __shfl_xor(lt_c, off);
        lb_c  += __shfl_xor(lb_c, off);
    }
    if (ln == 0) {
        sh.red[wv][0] = s_o2; sh.red[wv][1] = s_dot;
        atomicAdd(&sh.cnt[2], lt_c);
        atomicAdd(&sh.cnt[3], lb_c);
    }
    __syncthreads();                                   // B2

    const float t_o2  = sh.red[0][0] + sh.red[1][0] + sh.red[2][0] + sh.red[3][0];
    const float t_dot = sh.red[0][1] + sh.red[1][1] + sh.red[2][1] + sh.red[3][1];

    // ---- exactness fallback (pathological rows only): add middle bins ----
    if (sh.cnt[2] < (unsigned int)KSEL || sh.cnt[3] < (unsigned int)KSEL) {
        #pragma unroll
        for (int e = 0; e < EPW; ++e) {
            const unsigned int bits = __float_as_uint(z_r[e]) & 0x7fffffffu;
            const unsigned int b = bits >> 21;
            if (b < HI_T && b >= LO_T) atomicAdd(&sh.hist[b], 1u);
        }
        __syncthreads();
    }

    // ---- per-wave redundant scan (registers; no LDS publish, no barrier) ----
    unsigned int bt, bb, rT, rB;
    {
        unsigned int hv[16];
        {
            const uint4 h0 = *(const uint4*)&sh.hist[ln * 16 + 0];
            const uint4 h1 = *(const uint4*)&sh.hist[ln * 16 + 4];
            const uint4 h2 = *(const uint4*)&sh.hist[ln * 16 + 8];
            const uint4 h3 = *(const uint4*)&sh.hist[ln * 16 + 12];
            hv[0]=h0.x; hv[1]=h0.y; hv[2]=h0.z; hv[3]=h0.w;
            hv[4]=h1.x; hv[5]=h1.y; hv[6]=h1.z; hv[7]=h1.w;
            hv[8]=h2.x; hv[9]=h2.y; hv[10]=h2.z; hv[11]=h2.w;
            hv[12]=h3.x; hv[13]=h3.y; hv[14]=h3.z; hv[15]=h3.w;
        }
        unsigned int L = 0;
        #pragma unroll
        for (int j = 0; j < 16; ++j) L += hv[j];
        unsigned int v = L;
        #pragma unroll
        for (int off = 1; off < 64; off <<= 1) {
            const unsigned int t = __shfl_down(v, off);
            if (ln + off < 64) v += t;
        }
        const unsigned int S = v - L;            // count strictly above lane's bins
        const unsigned int G = __shfl(v, 0);     // total histogrammed
        const unsigned long long ballT = __ballot(v >= (unsigned int)KSEL);
        const int ltl = 63 - __clzll((unsigned long long)ballT);
        unsigned int bt_l = 0u, cg_l = 0u;
        if (ln == ltl) {
            unsigned int run = S;
            #pragma unroll
            for (int j = 15; j >= 0; --j) {
                const unsigned int rn = run + hv[j];
                if (run < (unsigned int)KSEL && rn >= (unsigned int)KSEL) {
                    bt_l = (unsigned int)(ln * 16 + j);
                    cg_l = run;
                }
                run = rn;
            }
        }
        bt = __shfl(bt_l, ltl);
        rT = (unsigned int)KSEL - __shfl(cg_l, ltl);

        const unsigned int PI = G - S;
        const unsigned long long ballB = __ballot(PI >= (unsigned int)KSEL);
        const int lbl = __ffsll((unsigned long long)ballB) - 1;
        unsigned int bb_l = 0u, cl_l = 0u;
        if (ln == lbl) {
            unsigned int run = PI - L;
            #pragma unroll
            for (int j = 0; j < 16; ++j) {
                const unsigned int rn = run + hv[j];
                if (run < (unsigned int)KSEL && rn >= (unsigned int)KSEL) {
                    bb_l = (unsigned int)(ln * 16 + j);
                    cl_l = run;
                }
                run = rn;
            }
        }
        bb = __shfl(bb_l, lbl);
        rB = (unsigned int)KSEL - __shfl(cl_l, lbl);
    }

    // ---- collect boundary-bin candidates (exact numpy z keys via x reload) ----
    // lists is a separate array (no union with hist) -> no barrier needed after scan
    #pragma unroll
    for (int e = 0; e < EPW; ++e) {
        const int i = e >> 2, j = e & 3;
        const unsigned int d = ((unsigned int)(i * TPB + tid) << 2) | (unsigned int)j;
        const unsigned int bits = __float_as_uint(z_r[e]) & 0x7fffffffu;
        const unsigned int b = bits >> 21;
        const bool isBt = (b == bt), isBb = (b == bb);
        if (isBt || isBb) {
            const float xx   = x[base + d];        // L2-hot reload, exact value
            const float mu   = ema_mean[d];
            const float stdp = ws[WS_STDP + d];
            const float zp   = __fdiv_rn(__fsub_rn(xx, mu), stdp);
            const unsigned int pb = __float_as_uint(zp) & 0x7fffffffu;
            if (isBt) {
                const unsigned int p = atomicAdd(&sh.cnt[0], 1u);
                if (p < CAP)
                    sh.lists[p] = ((unsigned long long)pb << 32) | (unsigned long long)(~d);
            } else {
                const unsigned int p = atomicAdd(&sh.cnt[1], 1u);
                if (p < CAP)
                    sh.lists[CAP + p] = ((unsigned long long)(~pb) << 32) | (unsigned long long)(~d);
            }
        }
    }
    __syncthreads();                                   // B3

    // ---- resolve in registers: wave0 -> top, wave1 -> bot; winners -> mark[] ----
    if (wv < 2) {
        const int ph = wv;
        const unsigned int r = (ph == 0) ? rT : rB;
        unsigned int m = sh.cnt[ph];
        if (m > CAP) m = CAP;
        unsigned long long key[NQ];
        #pragma unroll
        for (int q = 0; q < NQ; ++q) {
            const unsigned int p = (unsigned int)ln + ((unsigned int)q << 6);
            key[q] = (p < m) ? sh.lists[ph * CAP + p] : 0ull;
        }
        const unsigned char tag = (ph == 0) ? (unsigned char)1 : (unsigned char)2;
        for (unsigned int it = 0; it < r; ++it) {
            unsigned long long k = 0ull;
            #pragma unroll
            for (int q = 0; q < NQ; ++q) k = (key[q] > k) ? key[q] : k;
            #pragma unroll
            for (int off = 32; off; off >>= 1) {
                const unsigned long long o = __shfl_xor(k, off);
                if (o > k) k = o;
            }
            if (ln == 0) {
                const unsigned int d = ~((unsigned int)(k & 0xffffffffu));
                sh.mark[d & (D_DIM - 1)] = tag;
            }
            #pragma unroll
            for (int q = 0; q < NQ; ++q) if (key[q] == k) key[q] = 0ull;  // unique keys
        }
    }
    __syncthreads();                                   // B4

    // ---- final pass: reload x (L2-hot), recompute gelu, gate via bin + mark, store ----
    const float on = sqrtf(t_o2);
    float cs = (t_dot * inv_en) / fmaxf(on, 1e-12f);
    cs = fminf(fmaxf(cs, -1.0f), 1.0f);
    const float gc = expf(-tau * cs);

    #pragma unroll
    for (int i = 0; i < EPW / 4; ++i) {
        const int off = (i * TPB + tid) * 4;
        const float4 xv = *(const float4*)(x + base + off);
        const unsigned int mw = mrk32[i * TPB + tid];   // 4 mark bytes, packed
        const float xs[4] = {xv.x, xv.y, xv.z, xv.w};
        float ov[4];
        #pragma unroll
        for (int j = 0; j < 4; ++j) {
            const int e = i * 4 + j;
            const float zz = z_r[e];
            float og = gelu_fast(xs[j]);
            const unsigned int b = (__float_as_uint(zz) & 0x7fffffffu) >> 21;
            const unsigned int m = (mw >> (8 * j)) & 0xffu;
            if (m == 1u)      og *= top_gate(zz, beta_up, kg);
            else if (m == 2u) og *= beta_fam;
            else if (b > bt)  og *= top_gate(zz, beta_up, kg);
            else if (b < bb)  og *= beta_fam;
            ov[j] = og * gc;
        }
        float4 o4; o4.x = ov[0]; o4.y = ov[1]; o4.z = ov[2]; o4.w = ov[3];
        *(float4*)(out + base + off) = o4;
    }
}

extern "C" void kernel_launch(void* const* d_in, const int* in_sizes, int n_in,
                              void* d_out, int out_size, void* d_ws, size_t ws_size,
                              hipStream_t stream) {
    const float* x  = (const float*)d_in[0];
    const float* em = (const float*)d_in[1];
    const float* eq = (const float*)d_in[2];
    const float* eo = (const float*)d_in[3];
    const float* lt = (const float*)d_in[4];
    const float* lb = (const float*)d_in[5];
    const float* lg = (const float*)d_in[6];
    const float* lf = (const float*)d_in[7];
    float* o  = (float*)d_out;
    float* ws = (float*)d_ws;
    const int rows = in_sizes[0] / D_DIM;
    precomp<<<dim3(1), dim3(TPB), 0, stream>>>(em, eq, eo, lt, lb, lg, lf, ws);
    fused_gelu_gate<<<dim3(rows), dim3(TPB), 0, stream>>>(x, em, eo, ws, o);
}

// Round 6
// 317.652 us; speedup vs baseline: 1.1540x; 1.1540x over previous
//
#include <hip/hip_runtime.h>
#include <stdint.h>

#define TPB   512
#define D_DIM 4096
#define EPW   8        // elements per thread = D/TPB
#define NVEC  (EPW/4)  // 2
#define CAP   256      // candidate capacity per list
#define NQ    (CAP/64)
#define KSEL  16
#define THI0  2.5f     // top candidate threshold (true 16th ~3.2)
#define TLO0  0.02f    // bot candidate threshold (true 16th ~0.005)

// ws layout (floats)
#define WS_STDP 0
#define WS_INV  D_DIM
#define WS_SCAL (2*D_DIM)   // [0]=tau [1]=beta_up [2]=gamma [3]=beta_fam [4]=inv_e_norm

struct SMem {
    unsigned long long lists[2 * CAP];    // 4 KB: [0,CAP)=top, [CAP,2CAP)=bot
    unsigned char mark[D_DIM];            // 4 KB: 0=none 1=top-winner 2=bot-winner
    float red[8][2];
    unsigned int cnt[2];
};

__device__ __forceinline__ float fast_rcp(float v)  { return __builtin_amdgcn_rcpf(v); }
__device__ __forceinline__ float fast_exp2(float v) { return __builtin_amdgcn_exp2f(v); }

// gelu(x) = 0.5x(1+tanh(u)) = x * sigmoid(2u), u = c*(x + 0.044715 x^3)
#define GELU_AN (-2.30220819f)   // -2c*log2e
#define GELU_BN (-0.10294331f)   // -2c*0.044715*log2e
#define TWO_LOG2E (2.8853900817779268f)
#define LOG2E     (1.4426950408889634f)

__device__ __forceinline__ float gelu_fast(float x) {
    float x2 = x * x;
    float s  = fmaf(x2, GELU_BN, GELU_AN);
    float nq = x * s;
    float ex = fast_exp2(nq);
    return x * fast_rcp(1.0f + ex);
}

__device__ __forceinline__ float tanh_fast_pm(float y2l) {
    float ex = fast_exp2(y2l);
    float r  = fast_rcp(1.0f + ex);
    return fmaf(-2.0f, r, 1.0f);
}

__device__ __forceinline__ float top_gate(float zz, float beta_up, float kg) {
    float g = fmaf(beta_up, tanh_fast_pm(zz * kg), 1.0f);
    return fminf(fmaxf(g, 0.1f), 8.0f);
}

// ---- precompute: per-column stdp/inv + scalars (1 block) ----
__global__ __launch_bounds__(256) void precomp(
    const float* __restrict__ em, const float* __restrict__ eq,
    const float* __restrict__ eo,
    const float* __restrict__ lt, const float* __restrict__ lb,
    const float* __restrict__ lg, const float* __restrict__ lf,
    float* __restrict__ ws)
{
    __shared__ float red[4];
    const int tid = threadIdx.x;
    float e2 = 0.0f;
    for (int i = 0; i < D_DIM / 256; ++i) {
        const int d = i * 256 + tid;
        const float mu  = em[d];
        const float mu2 = __fmul_rn(mu, mu);
        float var = __fsub_rn(eq[d], mu2);
        var = fmaxf(var, 1e-4f);
        const float stdp = __fadd_rn(sqrtf(var), 1e-5f);  // bit-identical to numpy std+EPS
        ws[WS_STDP + d] = stdp;
        ws[WS_INV + d]  = 1.0f / stdp;
        const float e = eo[d];
        e2 = fmaf(e, e, e2);
    }
    #pragma unroll
    for (int off = 32; off; off >>= 1) e2 += __shfl_xor(e2, off);
    if ((tid & 63) == 0) red[tid >> 6] = e2;
    __syncthreads();
    if (tid == 0) {
        const float t  = red[0] + red[1] + red[2] + red[3];
        const float en = sqrtf(t);
        ws[WS_SCAL + 0] = expf(lt[0]);
        ws[WS_SCAL + 1] = log1pf(expf(lb[0]));
        ws[WS_SCAL + 2] = log1pf(expf(lg[0]));
        ws[WS_SCAL + 3] = 1.0f / (1.0f + expf(-lf[0]));
        ws[WS_SCAL + 4] = 1.0f / fmaxf(en, 1e-12f);
    }
}

__global__ __launch_bounds__(TPB) void fused_gelu_gate(
    const float* __restrict__ x,
    const float* __restrict__ ema_mean,
    const float* __restrict__ ema_out,
    const float* __restrict__ ws,
    float* __restrict__ out)
{
    __shared__ SMem sh;
    const int tid = threadIdx.x;
    const int ln  = tid & 63;
    const int wv  = tid >> 6;
    const long long base = (long long)blockIdx.x * D_DIM;

    // ---- init mark + counters ----
    unsigned int* mrk32 = (unsigned int*)sh.mark;
    #pragma unroll
    for (int i = 0; i < (D_DIM / 4) / TPB; ++i) mrk32[tid + i * TPB] = 0u;
    if (tid < 2) sh.cnt[tid] = 0u;
    __syncthreads();                                   // B1

    const float tau      = ws[WS_SCAL + 0];
    const float beta_up  = ws[WS_SCAL + 1];
    const float kg       = ws[WS_SCAL + 2] * TWO_LOG2E;  // gamma * 2log2e
    const float beta_fam = ws[WS_SCAL + 3];
    const float inv_en   = ws[WS_SCAL + 4];

    float thi = THI0, tlo = TLO0;
    float z_r[EPW];
    float s_o2 = 0.0f, s_dot = 0.0f;

    // ---- pass 1: load, fast gelu (sums), fast z (kept), threshold-collect ----
    #pragma unroll
    for (int i = 0; i < NVEC; ++i) {
        const int off = (i * TPB + tid) * 4;
        const float4 xv = *(const float4*)(x + base + off);
        const float4 mv = *(const float4*)(ema_mean + off);
        const float4 iv = *(const float4*)(ws + WS_INV + off);
        const float4 ev = *(const float4*)(ema_out + off);
        const float xs[4] = {xv.x, xv.y, xv.z, xv.w};
        const float ms[4] = {mv.x, mv.y, mv.z, mv.w};
        const float is[4] = {iv.x, iv.y, iv.z, iv.w};
        const float es[4] = {ev.x, ev.y, ev.z, ev.w};
        #pragma unroll
        for (int j = 0; j < 4; ++j) {
            const int e = i * 4 + j;
            const float xx = xs[j];
            const float zz = (xx - ms[j]) * is[j];
            const float og = gelu_fast(xx);
            z_r[e] = zz;
            s_o2  = fmaf(og, og, s_o2);
            s_dot = fmaf(og, es[j], s_dot);
            const float az = fabsf(zz);
            if (az >= thi || az <= tlo) {
                const unsigned int d = (unsigned int)(off + j);
                const float stdp = ws[WS_STDP + d];
                const float zp   = __fdiv_rn(__fsub_rn(xx, ms[j]), stdp);
                const unsigned int pb = __float_as_uint(zp) & 0x7fffffffu;
                if (az >= thi) {
                    const unsigned int p = atomicAdd(&sh.cnt[0], 1u);
                    if (p < CAP)
                        sh.lists[p] = ((unsigned long long)pb << 32) | (unsigned long long)(~d);
                } else {
                    const unsigned int p = atomicAdd(&sh.cnt[1], 1u);
                    if (p < CAP)
                        sh.lists[CAP + p] = ((unsigned long long)(~pb) << 32) | (unsigned long long)(~d);
                }
            }
        }
    }

    // ---- block-reduce sums ----
    #pragma unroll
    for (int off = 32; off; off >>= 1) {
        s_o2  += __shfl_xor(s_o2, off);
        s_dot += __shfl_xor(s_dot, off);
    }
    if (ln == 0) { sh.red[wv][0] = s_o2; sh.red[wv][1] = s_dot; }
    __syncthreads();                                   // B2

    float t_o2 = 0.0f, t_dot = 0.0f;
    #pragma unroll
    for (int w = 0; w < TPB / 64; ++w) { t_o2 += sh.red[w][0]; t_dot += sh.red[w][1]; }

    // ---- fallback (uniform branch; never taken for sane inputs): re-collect ----
    unsigned int cT = sh.cnt[0], cB = sh.cnt[1];
    int tries = 0;
    while ((cT < (unsigned)KSEL || cT > (unsigned)CAP ||
            cB < (unsigned)KSEL || cB > (unsigned)CAP) && tries < 20) {
        if (cT < (unsigned)KSEL) thi *= 0.5f; else if (cT > (unsigned)CAP) thi *= 1.5f;
        if (cB < (unsigned)KSEL) tlo *= 2.0f; else if (cB > (unsigned)CAP) tlo *= 0.6666f;
        __syncthreads();
        if (tid < 2) sh.cnt[tid] = 0u;
        __syncthreads();
        #pragma unroll
        for (int e = 0; e < EPW; ++e) {
            const float az = fabsf(z_r[e]);
            if (az >= thi || az <= tlo) {
                const unsigned int d = (unsigned int)(((e >> 2) * TPB + tid) * 4 + (e & 3));
                const float xx   = x[base + d];
                const float mu   = ema_mean[d];
                const float stdp = ws[WS_STDP + d];
                const float zp   = __fdiv_rn(__fsub_rn(xx, mu), stdp);
                const unsigned int pb = __float_as_uint(zp) & 0x7fffffffu;
                if (az >= thi) {
                    const unsigned int p = atomicAdd(&sh.cnt[0], 1u);
                    if (p < CAP)
                        sh.lists[p] = ((unsigned long long)pb << 32) | (unsigned long long)(~d);
                } else {
                    const unsigned int p = atomicAdd(&sh.cnt[1], 1u);
                    if (p < CAP)
                        sh.lists[CAP + p] = ((unsigned long long)(~pb) << 32) | (unsigned long long)(~d);
                }
            }
        }
        __syncthreads();
        cT = sh.cnt[0]; cB = sh.cnt[1];
        ++tries;
    }

    // ---- resolve top-16 / bot-16 in registers: wave0 -> top, wave1 -> bot ----
    if (wv < 2) {
        const int ph = wv;
        unsigned int m = sh.cnt[ph];
        if (m > CAP) m = CAP;
        unsigned long long key[NQ];
        #pragma unroll
        for (int q = 0; q < NQ; ++q) {
            const unsigned int p = (unsigned int)ln + ((unsigned int)q << 6);
            key[q] = (p < m) ? sh.lists[ph * CAP + p] : 0ull;
        }
        const unsigned char tag = (ph == 0) ? (unsigned char)1 : (unsigned char)2;
        #pragma unroll 1
        for (int it = 0; it < KSEL; ++it) {
            unsigned long long k = 0ull;
            #pragma unroll
            for (int q = 0; q < NQ; ++q) k = (key[q] > k) ? key[q] : k;
            #pragma unroll
            for (int off = 32; off; off >>= 1) {
                const unsigned long long o = __shfl_xor(k, off);
                if (o > k) k = o;
            }
            if (ln == 0) {
                const unsigned int d = ~((unsigned int)(k & 0xffffffffu));
                sh.mark[d & (D_DIM - 1)] = tag;
            }
            #pragma unroll
            for (int q = 0; q < NQ; ++q) if (key[q] == k) key[q] = 0ull;  // unique keys
        }
    }
    __syncthreads();                                   // B3

    // ---- final pass: reload x (L2-hot), recompute gelu, apply mark + cos gate ----
    const float on = sqrtf(t_o2);
    float cs = (t_dot * inv_en) / fmaxf(on, 1e-12f);
    cs = fminf(fmaxf(cs, -1.0f), 1.0f);
    const float gc = fast_exp2(-tau * cs * LOG2E);

    #pragma unroll
    for (int i = 0; i < NVEC; ++i) {
        const int off = (i * TPB + tid) * 4;
        const float4 xv = *(const float4*)(x + base + off);
        const unsigned int mw = mrk32[i * TPB + tid];   // 4 mark bytes, packed
        const float xs[4] = {xv.x, xv.y, xv.z, xv.w};
        float ov[4];
        #pragma unroll
        for (int j = 0; j < 4; ++j) {
            const int e = i * 4 + j;
            float og = gelu_fast(xs[j]);
            const unsigned int m = (mw >> (8 * j)) & 0xffu;
            if (m == 1u)      og *= top_gate(z_r[e], beta_up, kg);
            else if (m == 2u) og *= beta_fam;
            ov[j] = og * gc;
        }
        float4 o4; o4.x = ov[0]; o4.y = ov[1]; o4.z = ov[2]; o4.w = ov[3];
        *(float4*)(out + base + off) = o4;
    }
}

extern "C" void kernel_launch(void* const* d_in, const int* in_sizes, int n_in,
                              void* d_out, int out_size, void* d_ws, size_t ws_size,
                              hipStream_t stream) {
    const float* x  = (const float*)d_in[0];
    const float* em = (const float*)d_in[1];
    const float* eq = (const float*)d_in[2];
    const float* eo = (const float*)d_in[3];
    const float* lt = (const float*)d_in[4];
    const float* lb = (const float*)d_in[5];
    const float* lg = (const float*)d_in[6];
    const float* lf = (const float*)d_in[7];
    float* o  = (float*)d_out;
    float* ws = (float*)d_ws;
    const int rows = in_sizes[0] / D_DIM;
    precomp<<<dim3(1), dim3(256), 0, stream>>>(em, eq, eo, lt, lb, lg, lf, ws);
    fused_gelu_gate<<<dim3(rows), dim3(TPB), 0, stream>>>(x, em, eo, ws, o);
}